// Round 15
// baseline (297.663 us; speedup 1.0000x reference)
//
#include <hip/hip_runtime.h>
#include <hip/hip_bf16.h>

#define NN 100000
#define NE 1600000
#define HD 64
#define NBKT 391            // buckets of 256 dst nodes
#define EPBKT 8192          // fixed ebuf slots per bucket (max bucket ~4500)
#define EPB 8192            // edges per phaseA block
#define NBLKA ((NE + EPB - 1) / EPB)   // 196
#define NMBLK ((NN + 63) / 64)         // 1563
#define TANH_C 2.885390081777927f      // 2*log2(e); tanh(x)=1-2/(exp2(c*x)+1)
#define HALF_C 1.4426950408889634f     // log2(e) = TANH_C/2: half-exponent factor

// half2 type exactly as the builtins define it
using h2 = decltype(__builtin_amdgcn_cvt_pkrtz(0.f, 0.f));

__device__ __forceinline__ float fast_tanh(float x) {
    float t = __builtin_amdgcn_exp2f(x * TANH_C);
    return 1.f - 2.f * __builtin_amdgcn_rcpf(t + 1.f);
}
__device__ __forceinline__ float bf2f(unsigned short u) {
    return __uint_as_float(((unsigned)u) << 16);
}
__device__ __forceinline__ unsigned short f2bf(float f) {
    unsigned u = __float_as_uint(f);
    return (unsigned short)((u + 0x7FFFu + ((u >> 16) & 1u)) >> 16);
}
__device__ __forceinline__ unsigned pkh(float a, float b) {   // pack 2 f32 -> f16x2
    union { h2 h; unsigned u; } c;
    c.h = __builtin_amdgcn_cvt_pkrtz(a, b);
    return c.u;
}
__device__ __forceinline__ h2 u2h(unsigned u) {
    union { unsigned u; h2 h; } c; c.u = u; return c.h;
}
// HALF-exponent of the sigmoid argument: 2^{clamp(z/2, +-126)} with z = c*acc.
// Each factor finite & nonzero; product p = EA*EB = 2^{(za+zb)/2} is in f32 range
// whenever |za+zb| <= 252; squaring AFTER the product keeps cross-cancellation
// exact. Per-side clamp only matters if a single |z| > 252 (dot > 87: unreachable).
// NOTE: EA may be bf16 (per-source error averages out across the neighbor sum);
// EB must stay f32 (its error is coherent across the whole sum -- R7 failure).
__device__ __forceinline__ float exph(float a) {
    float z = a * HALF_C;
    z = fminf(fmaxf(z, -126.f), 126.f);
    return __builtin_amdgcn_exp2f(z);
}

// ---------------- generic zero ----------------
__global__ __launch_bounds__(256)
void k_zero(int* __restrict__ g, int n) {
    int t = blockIdx.x * 256 + threadIdx.x;
    if (t < n) g[t] = 0;
}

// ---------------- edge CSR build (2-pass, validated) ----------------
__global__ __launch_bounds__(256)
void k_phaseA(const int* __restrict__ src, const int* __restrict__ dst,
              int* __restrict__ gcur, unsigned int* __restrict__ ebuf) {
    __shared__ int cnt[NBKT];
    __shared__ int base[NBKT];
    __shared__ int dl[EPB];
    int tid = threadIdx.x;
    for (int i = tid; i < NBKT; i += 256) cnt[i] = 0;
    int b0 = blockIdx.x * EPB;
    int end = min(b0 + EPB, NE);
    int n = end - b0;
    for (int i = tid; i < n; i += 256) dl[i] = dst[b0 + i];
    __syncthreads();
    for (int i = tid; i < n; i += 256)
        atomicAdd(&cnt[dl[i] >> 8], 1);
    __syncthreads();
    for (int i = tid; i < NBKT; i += 256) {
        int c = cnt[i];
        base[i] = c ? (i * EPBKT + atomicAdd(&gcur[i], c)) : 0;
    }
    __syncthreads();
    for (int i = tid; i < NBKT; i += 256) cnt[i] = 0;
    __syncthreads();
    for (int i = tid; i < n; i += 256) {
        int d = dl[i];
        int b = d >> 8;
        int pos = base[b] + atomicAdd(&cnt[b], 1);
        ebuf[pos] = (unsigned)src[b0 + i] | ((unsigned)(d & 255) << 24);
    }
}

// bscan also fills A's sentinel row (node NN) with bf16 +inf: edge-kernel pad
// lanes gather this row and produce exactly-zero terms (rcp(inf) = 0).
__global__ __launch_bounds__(512)
void k_bscan(const int* __restrict__ gcur, int* __restrict__ gbase,
             int* __restrict__ starts, unsigned short* __restrict__ A) {
    __shared__ int tmp[2][512];
    int t = threadIdx.x;
    if (t < HD) A[(size_t)NN * HD + t] = 0x7F80;   // bf16 +inf sentinel row
    int v = (t < NBKT) ? gcur[t] : 0;
    int p = 0;
    tmp[0][t] = v;
    __syncthreads();
#pragma unroll
    for (int off = 1; off < 512; off <<= 1) {
        int nv = tmp[p][t] + ((t >= off) ? tmp[p][t - off] : 0);
        tmp[p ^ 1][t] = nv; p ^= 1;
        __syncthreads();
    }
    if (t < NBKT) gbase[t] = tmp[p][t] - v;
    if (t == 0) { gbase[NBKT] = NE; starts[NN] = NE; }
}

__global__ __launch_bounds__(256)
void k_phaseB(const unsigned int* __restrict__ ebuf, const int* __restrict__ gcur,
              const int* __restrict__ gbase, int* __restrict__ starts,
              int* __restrict__ ssrc) {
    __shared__ int hist[256];
    __shared__ int tmp[2][256];
    __shared__ int cur[256];
    int b = blockIdx.x;
    int eb0 = b * EPBKT;
    int cntb = gcur[b];
    int go = gbase[b];
    int t = threadIdx.x;
    hist[t] = 0;
    __syncthreads();
    for (int i = t; i < cntb; i += 256)
        atomicAdd(&hist[ebuf[eb0 + i] >> 24], 1);
    __syncthreads();
    int v = hist[t];
    int p = 0;
    tmp[0][t] = v;
    __syncthreads();
#pragma unroll
    for (int off = 1; off < 256; off <<= 1) {
        int nv = tmp[p][t] + ((t >= off) ? tmp[p][t - off] : 0);
        tmp[p ^ 1][t] = nv; p ^= 1;
        __syncthreads();
    }
    int excl = tmp[p][t] - v;
    cur[t] = excl;
    int node = b * 256 + t;
    if (node < NN) starts[node] = go + excl;
    __syncthreads();
    for (int i = t; i < cntb; i += 256) {
        unsigned e = ebuf[eb0 + i];
        int ld = e >> 24;
        int pos = go + atomicAdd(&cur[ld], 1);
        ssrc[pos] = e & 0xFFFFFF;
    }
}

// ---- node GEMM via v_dot2_f32_f16: operands packed f16-pairs along K in LDS ----
// If x != null (layer 1): h-tile computed on the fly as tanh(x@Wi+bi) -- h array
// is not touched (k_input is fused away).  Otherwise reads h (updated in place
// by the previous k_edge).
// A-output holds EA = 2^{clamp(c*(h@Wtop + b)/2, +-126)} as bf16.
// B-output holds EB = 2^{clamp(c*(h@Wbot)/2,     +-126)} as f32.
// Edge sigmoid term becomes 1/(1 + (EA*EB)^2): no exp2 in the edge loop.
__global__ __launch_bounds__(256)
void k_nodemm(const float* __restrict__ h, const float* __restrict__ x,
              const float* __restrict__ Wi, const float* __restrict__ bi,
              const float* __restrict__ W, const float* __restrict__ bias,
              unsigned short* __restrict__ A, float* __restrict__ B) {
    __shared__ unsigned ht_p[32][68];      // [k-pair][row(+pad)]  8.7 KB
    __shared__ unsigned ws_p[2][32][64];   // [half][k-pair][col]  16.4 KB
    int m0 = blockIdx.x * 64;
    int tid = threadIdx.x;
    const float4* W4 = (const float4*)W;
    // stage W packed along K: (h,k2,c4), 1024 tasks
    for (int i = tid; i < 1024; i += 256) {
        int c4 = i & 15, k2 = (i >> 4) & 31, hh = i >> 9;
        float4 a = W4[(hh * 64 + 2 * k2) * 16 + c4];
        float4 b = W4[(hh * 64 + 2 * k2 + 1) * 16 + c4];
        uint4 pk;
        pk.x = pkh(a.x, b.x); pk.y = pkh(a.y, b.y);
        pk.z = pkh(a.z, b.z); pk.w = pkh(a.w, b.w);
        *(uint4*)&ws_p[hh][k2][c4 * 4] = pk;
    }
    // stage h tile, packed along K, transposed (layer 1: compute from x)
    for (int i = tid; i < 1024; i += 256) {
        int r = i >> 4, c4 = i & 15;
        int row = m0 + r;
        float4 v = make_float4(0.f, 0.f, 0.f, 0.f);
        if (row < NN) {
            if (x) {
                float4 xv = ((const float4*)x)[row];
                float4 w0 = ((const float4*)Wi)[0 * 16 + c4];
                float4 w1 = ((const float4*)Wi)[1 * 16 + c4];
                float4 w2 = ((const float4*)Wi)[2 * 16 + c4];
                float4 w3 = ((const float4*)Wi)[3 * 16 + c4];
                float4 bb = ((const float4*)bi)[c4];
                v.x = fast_tanh(bb.x + xv.x * w0.x + xv.y * w1.x + xv.z * w2.x + xv.w * w3.x);
                v.y = fast_tanh(bb.y + xv.x * w0.y + xv.y * w1.y + xv.z * w2.y + xv.w * w3.y);
                v.z = fast_tanh(bb.z + xv.x * w0.z + xv.y * w1.z + xv.z * w2.z + xv.w * w3.z);
                v.w = fast_tanh(bb.w + xv.x * w0.w + xv.y * w1.w + xv.z * w2.w + xv.w * w3.w);
            } else {
                v = ((const float4*)h)[row * 16 + c4];
            }
        }
        ht_p[2 * c4][r]     = pkh(v.x, v.y);
        ht_p[2 * c4 + 1][r] = pkh(v.z, v.w);
    }
    __syncthreads();
    int tn = tid & 15;
    int tm = tid >> 4;
    bool isA = (tn < 8);
    const unsigned* Wb = &ws_p[isA ? 0 : 1][0][(tn & 7) * 8];
    float acc[4][8];
#pragma unroll
    for (int i = 0; i < 4; ++i)
#pragma unroll
        for (int j = 0; j < 8; ++j)
            acc[i][j] = isA ? bias[(tn & 7) * 8 + j] : 0.f;
#pragma unroll 8
    for (int k2 = 0; k2 < 32; ++k2) {
        uint4 hv = *(const uint4*)&ht_p[k2][tm * 4];
        uint4 w0 = *(const uint4*)&Wb[k2 * 64];
        uint4 w1 = *(const uint4*)&Wb[k2 * 64 + 4];
        h2 hh[4] = {u2h(hv.x), u2h(hv.y), u2h(hv.z), u2h(hv.w)};
        h2 ww[8] = {u2h(w0.x), u2h(w0.y), u2h(w0.z), u2h(w0.w),
                    u2h(w1.x), u2h(w1.y), u2h(w1.z), u2h(w1.w)};
#pragma unroll
        for (int i = 0; i < 4; ++i)
#pragma unroll
            for (int j = 0; j < 8; ++j)
                acc[i][j] = __builtin_amdgcn_fdot2(hh[i], ww[j], acc[i][j], false);
    }
#pragma unroll
    for (int i = 0; i < 4; ++i) {
        int node = m0 + tm * 4 + i;
        if (node >= NN) break;
        if (isA) {
            uint4 pk;
            pk.x = (unsigned)f2bf(exph(acc[i][0])) | ((unsigned)f2bf(exph(acc[i][1])) << 16);
            pk.y = (unsigned)f2bf(exph(acc[i][2])) | ((unsigned)f2bf(exph(acc[i][3])) << 16);
            pk.z = (unsigned)f2bf(exph(acc[i][4])) | ((unsigned)f2bf(exph(acc[i][5])) << 16);
            pk.w = (unsigned)f2bf(exph(acc[i][6])) | ((unsigned)f2bf(exph(acc[i][7])) << 16);
            ((uint4*)A)[node * 8 + tn] = pk;
        } else {
            ((float4*)B)[node * 16 + (tn & 7) * 2 + 0] =
                make_float4(exph(acc[i][0]), exph(acc[i][1]),
                            exph(acc[i][2]), exph(acc[i][3]));
            ((float4*)B)[node * 16 + (tn & 7) * 2 + 1] =
                make_float4(exph(acc[i][4]), exph(acc[i][5]),
                            exph(acc[i][6]), exph(acc[i][7]));
        }
    }
}

// -------- edge kernel: applies the aggregation delta to h IN PLACE --------
// term = 1/(1 + (EA[s,j]*EB[d,j])^2); mul+fma+rcp+add per element (no exp2).
// deg <= 32 (99.99% of nodes): the ENTIRE node is one self-contained padded
// block -> ONE vmcnt latency group.  Pad lanes carry idx = NN -> +inf
// sentinel row -> term exactly 0.  m is wave-uniform: non-divergent switch.
// If W1 != null (last layer): output MLP fused, wave-local (no end barrier).
// R14 lesson: the epilogue cost was LDS ISSUE COUNT (64 scalar ds_read_b32
// per wave x 100K waves ~ 22 us).  Now 16 LDS ops: W1 staged as ws_q[8][64][4]
// so thread j reads its column's 4 k-pairs as ONE ds_read_b128 (contiguous,
// conflict-free); h_new pairs in ht_c[4][32] read as 8 broadcast b128s.
// fdot2 order k2 = 4*k4+{0,1,2,3} ascending = identical accumulation order.
#define BODYN(N) { \
    unsigned short va[N]; \
    _Pragma("unroll") \
    for (int u = 0; u < N; ++u) { \
        int s = __builtin_amdgcn_readlane(idx, k + u); \
        va[u] = A[s * HD + j]; \
    } \
    _Pragma("unroll") \
    for (int u = 0; u < N; u += 2) { \
        float pa = bf2f(va[u]) * eb; \
        float pb = bf2f(va[u + 1]) * eb; \
        acc0 += __builtin_amdgcn_rcpf(fmaf(pa, pa, 1.f)); \
        acc1 += __builtin_amdgcn_rcpf(fmaf(pb, pb, 1.f)); \
    } \
}

__global__ __launch_bounds__(256)
void k_edge(const unsigned short* __restrict__ A, const float* __restrict__ B,
            float* __restrict__ h,
            const int* __restrict__ starts, const int* __restrict__ ssrc,
            const float* __restrict__ x, const float* __restrict__ Wi,
            const float* __restrict__ bi,
            const float* __restrict__ W1, const float* __restrict__ b1,
            const float* __restrict__ W2, const float* __restrict__ b2,
            float* __restrict__ out) {
    __shared__ unsigned ws_q[8][64][4];   // W1 f16-pairs, col-major quads, 8 KB
    __shared__ unsigned ht_c[4][32];      // h_new pairs, one row per wave, 512 B
    int g = blockIdx.x * 256 + threadIdx.x;
    int d = g >> 6, j = g & 63;
    if (d >= NN) return;   // never taken: grid is exact (NN*HD % 256 == 0)
    if (W1) {              // stage W1: task = (k4, col); coalesced reads,
                           // conflict-free b128-pattern writes
        for (int i = threadIdx.x; i < 512; i += 256) {
            int c = i & 63, k4 = i >> 6;
            uint4 pk;
            pk.x = pkh(W1[(8 * k4 + 0) * HD + c], W1[(8 * k4 + 1) * HD + c]);
            pk.y = pkh(W1[(8 * k4 + 2) * HD + c], W1[(8 * k4 + 3) * HD + c]);
            pk.z = pkh(W1[(8 * k4 + 4) * HD + c], W1[(8 * k4 + 5) * HD + c]);
            pk.w = pkh(W1[(8 * k4 + 6) * HD + c], W1[(8 * k4 + 7) * HD + c]);
            *(uint4*)&ws_q[k4][c][0] = pk;
        }
        __syncthreads();   // waves still in lockstep here: ~free
    }
    int s0 = starts[d], s1 = starts[d + 1];
    float eb = B[d * HD + j];
    float hv;
    if (x) {
        float x0 = x[d * 4 + 0], x1 = x[d * 4 + 1];
        float x2 = x[d * 4 + 2], x3 = x[d * 4 + 3];
        hv = fast_tanh(bi[j] + x0 * Wi[j] + x1 * Wi[HD + j]
                             + x2 * Wi[2 * HD + j] + x3 * Wi[3 * HD + j]);
    } else {
        hv = h[d * HD + j];
    }
    float acc0 = 0.f, acc1 = 0.f;
    for (int base = s0; base < s1; base += 64) {
        int m = min(s1 - base, 64);
        int idx = (base + j < s1) ? ssrc[base + j] : NN;   // pad lanes -> sentinel
        if (m <= 32) {
            // whole node in ONE latency group (4-granular pad, ~9% overhead)
            int k = 0;
            int nq = (m + 3) >> 2;           // 1..8 quads
            switch (nq) {
                case 1: BODYN(4)  break;
                case 2: BODYN(8)  break;
                case 3: BODYN(12) break;
                case 4: BODYN(16) break;
                case 5: BODYN(20) break;
                case 6: BODYN(24) break;
                case 7: BODYN(28) break;
                default: BODYN(32) break;
            }
        } else {
            int k = 0;
            for (; k + 16 <= m; k += 16) {
                unsigned short va[16];
#pragma unroll
                for (int u = 0; u < 16; ++u) {
                    int s = __builtin_amdgcn_readlane(idx, k + u);   // SGPR src id
                    va[u] = A[s * HD + j];                           // one load group
                }
#pragma unroll
                for (int u = 0; u < 16; u += 2) {
                    float pa = bf2f(va[u]) * eb;
                    float pb = bf2f(va[u + 1]) * eb;
                    acc0 += __builtin_amdgcn_rcpf(fmaf(pa, pa, 1.f));
                    acc1 += __builtin_amdgcn_rcpf(fmaf(pb, pb, 1.f));
                }
            }
            int r = m - k;                       // 0..15
            if (r) {
                int nq = (r + 3) >> 2;           // 1..4 quads, padded w/ sentinel
                if (nq == 4)      BODYN(16)
                else if (nq == 3) BODYN(12)
                else if (nq == 2) BODYN(8)
                else              BODYN(4)
            }
        }
    }
    float delta = (float)(s1 - s0) - 2.f * (acc0 + acc1);
    float hnew = hv + delta;
    if (!W1) {
        h[d * HD + j] = hnew;
        return;
    }
    // ---- fused output MLP (wave-local, vectorized LDS, no block barrier) ----
    int nl = threadIdx.x >> 6;                   // this wave's ht_c row
    float partner = __shfl_down(hnew, 1);
    if ((j & 1) == 0) ht_c[nl][j >> 1] = pkh(hnew, partner);
    // same-wave LDS RAW: lgkmcnt ordering suffices (no __syncthreads)
    float acc = b1[j];                           // thread computes column c = j
#pragma unroll
    for (int k4 = 0; k4 < 8; ++k4) {
        uint4 hv4 = *(const uint4*)&ht_c[nl][k4 * 4];   // broadcast b128
        uint4 wv4 = *(const uint4*)&ws_q[k4][j][0];     // contiguous b128
        acc = __builtin_amdgcn_fdot2(u2h(hv4.x), u2h(wv4.x), acc, false);
        acc = __builtin_amdgcn_fdot2(u2h(hv4.y), u2h(wv4.y), acc, false);
        acc = __builtin_amdgcn_fdot2(u2h(hv4.z), u2h(wv4.z), acc, false);
        acc = __builtin_amdgcn_fdot2(u2h(hv4.w), u2h(wv4.w), acc, false);
    }
    float t1 = fast_tanh(acc);
    float p0 = t1 * W2[j * 3 + 0];
    float p1 = t1 * W2[j * 3 + 1];
    float p2 = t1 * W2[j * 3 + 2];
#pragma unroll
    for (int off = 1; off < 64; off <<= 1) {
        p0 += __shfl_xor(p0, off);
        p1 += __shfl_xor(p1, off);
        p2 += __shfl_xor(p2, off);
    }
    if (j == 0) {
        out[d * 3 + 0] = p0 + b2[0];
        out[d * 3 + 1] = p1 + b2[1];
        out[d * 3 + 2] = p2 + b2[2];
    }
}
#undef BODYN

extern "C" void kernel_launch(void* const* d_in, const int* in_sizes, int n_in,
                              void* d_out, int out_size, void* d_ws, size_t ws_size,
                              hipStream_t stream) {
    const float* x   = (const float*)d_in[0];
    const int*   ei  = (const int*)d_in[1];
    const float* Win = (const float*)d_in[2];
    const float* bin = (const float*)d_in[3];
    const float* Ws  = (const float*)d_in[4];
    const float* bs  = (const float*)d_in[5];
    const float* Wo1 = (const float*)d_in[6];
    const float* bo1 = (const float*)d_in[7];
    const float* Wo2 = (const float*)d_in[8];
    const float* bo2 = (const float*)d_in[9];
    float* out = (float*)d_out;

    char* p = (char*)d_ws;
    auto alloc = [&](size_t bytes) {
        char* r = p;
        p += (bytes + 15) & ~size_t(15);
        return r;
    };
    // total ~83.7 MB (proven-safe envelope); A has +1 sentinel row
    float* h            = (float*)alloc((size_t)NN * HD * 4);            // 25.6 MB
    float* Bm           = (float*)alloc((size_t)NN * HD * 4);            // 25.6 MB
    unsigned short* A   = (unsigned short*)alloc((size_t)(NN + 1) * HD * 2); // 12.8 MB
    unsigned int* ebuf  = (unsigned int*)alloc((size_t)NBKT * EPBKT * 4);// 12.81 MB
    int* starts         = (int*)alloc((size_t)(NN + 1) * 4);             // 0.4 MB
    int* ssrc           = (int*)alloc((size_t)NE * 4);                   // 6.4 MB
    int* gcur           = (int*)alloc((NBKT + 1) * 4);
    int* gbase          = (int*)alloc((NBKT + 1) * 4);

    const int* src = ei;
    const int* dst = ei + NE;

    // ---- edge CSR build (+ sentinel-row fill in k_bscan) ----
    k_zero<<<(NBKT + 255) / 256, 256, 0, stream>>>(gcur, NBKT);
    k_phaseA<<<NBLKA, 256, 0, stream>>>(src, dst, gcur, ebuf);
    k_bscan<<<1, 512, 0, stream>>>(gcur, gbase, starts, A);
    k_phaseB<<<NBKT, 256, 0, stream>>>(ebuf, gcur, gbase, starts, ssrc);

    // ---- pipeline (k_input fused into L1; out-MLP fused into L3 k_edge) ----
    k_nodemm<<<NMBLK, 256, 0, stream>>>(h, x, Win, bin, Ws, bs, A, Bm);
    k_edge<<<(NN * HD + 255) / 256, 256, 0, stream>>>(A, Bm, h, starts, ssrc, x, Win, bin,
                                                      nullptr, nullptr, nullptr, nullptr, nullptr);

    k_nodemm<<<NMBLK, 256, 0, stream>>>(h, nullptr, nullptr, nullptr,
                                        Ws + (size_t)1 * 2 * HD * HD, bs + HD, A, Bm);
    k_edge<<<(NN * HD + 255) / 256, 256, 0, stream>>>(A, Bm, h, starts, ssrc,
                                                      nullptr, nullptr, nullptr,
                                                      nullptr, nullptr, nullptr, nullptr, nullptr);

    k_nodemm<<<NMBLK, 256, 0, stream>>>(h, nullptr, nullptr, nullptr,
                                        Ws + (size_t)2 * 2 * HD * HD, bs + 2 * HD, A, Bm);
    k_edge<<<(NN * HD + 255) / 256, 256, 0, stream>>>(A, Bm, h, starts, ssrc,
                                                      nullptr, nullptr, nullptr,
                                                      Wo1, bo1, Wo2, bo2, out);
}

// Round 16
// 276.750 us; speedup vs baseline: 1.0756x; 1.0756x over previous
//
#include <hip/hip_runtime.h>
#include <hip/hip_bf16.h>

#define NN 100000
#define NE 1600000
#define HD 64
#define NBKT 391            // buckets of 256 dst nodes
#define EPBKT 8192          // fixed ebuf slots per bucket (max bucket ~4500)
#define EPB 8192            // edges per phaseA block
#define NBLKA ((NE + EPB - 1) / EPB)   // 196
#define NMBLK ((NN + 63) / 64)         // 1563
#define TANH_C 2.885390081777927f      // 2*log2(e); tanh(x)=1-2/(exp2(c*x)+1)
#define HALF_C 1.4426950408889634f     // log2(e) = TANH_C/2: half-exponent factor

// half2 type exactly as the builtins define it
using h2 = decltype(__builtin_amdgcn_cvt_pkrtz(0.f, 0.f));

__device__ __forceinline__ float fast_tanh(float x) {
    float t = __builtin_amdgcn_exp2f(x * TANH_C);
    return 1.f - 2.f * __builtin_amdgcn_rcpf(t + 1.f);
}
__device__ __forceinline__ float bf2f(unsigned short u) {
    return __uint_as_float(((unsigned)u) << 16);
}
__device__ __forceinline__ unsigned short f2bf(float f) {
    unsigned u = __float_as_uint(f);
    return (unsigned short)((u + 0x7FFFu + ((u >> 16) & 1u)) >> 16);
}
__device__ __forceinline__ unsigned pkh(float a, float b) {   // pack 2 f32 -> f16x2
    union { h2 h; unsigned u; } c;
    c.h = __builtin_amdgcn_cvt_pkrtz(a, b);
    return c.u;
}
__device__ __forceinline__ h2 u2h(unsigned u) {
    union { unsigned u; h2 h; } c; c.u = u; return c.h;
}
// HALF-exponent of the sigmoid argument: 2^{clamp(z/2, +-126)} with z = c*acc.
// Each factor finite & nonzero; product p = EA*EB = 2^{(za+zb)/2} is in f32 range
// whenever |za+zb| <= 252; squaring AFTER the product keeps cross-cancellation
// exact. Per-side clamp only matters if a single |z| > 252 (dot > 87: unreachable).
// NOTE: EA may be bf16 (per-source error averages out across the neighbor sum);
// EB must stay f32 (its error is coherent across the whole sum -- R7 failure).
__device__ __forceinline__ float exph(float a) {
    float z = a * HALF_C;
    z = fminf(fmaxf(z, -126.f), 126.f);
    return __builtin_amdgcn_exp2f(z);
}

// ---------------- generic zero ----------------
__global__ __launch_bounds__(256)
void k_zero(int* __restrict__ g, int n) {
    int t = blockIdx.x * 256 + threadIdx.x;
    if (t < n) g[t] = 0;
}

// ---------------- edge CSR build (2-pass, validated) ----------------
__global__ __launch_bounds__(256)
void k_phaseA(const int* __restrict__ src, const int* __restrict__ dst,
              int* __restrict__ gcur, unsigned int* __restrict__ ebuf) {
    __shared__ int cnt[NBKT];
    __shared__ int base[NBKT];
    __shared__ int dl[EPB];
    int tid = threadIdx.x;
    for (int i = tid; i < NBKT; i += 256) cnt[i] = 0;
    int b0 = blockIdx.x * EPB;
    int end = min(b0 + EPB, NE);
    int n = end - b0;
    for (int i = tid; i < n; i += 256) dl[i] = dst[b0 + i];
    __syncthreads();
    for (int i = tid; i < n; i += 256)
        atomicAdd(&cnt[dl[i] >> 8], 1);
    __syncthreads();
    for (int i = tid; i < NBKT; i += 256) {
        int c = cnt[i];
        base[i] = c ? (i * EPBKT + atomicAdd(&gcur[i], c)) : 0;
    }
    __syncthreads();
    for (int i = tid; i < NBKT; i += 256) cnt[i] = 0;
    __syncthreads();
    for (int i = tid; i < n; i += 256) {
        int d = dl[i];
        int b = d >> 8;
        int pos = base[b] + atomicAdd(&cnt[b], 1);
        ebuf[pos] = (unsigned)src[b0 + i] | ((unsigned)(d & 255) << 24);
    }
}

// bscan also fills A's sentinel row (node NN) with bf16 +inf: edge-kernel pad
// lanes gather this row and produce exactly-zero terms (rcp(inf) = 0).
__global__ __launch_bounds__(512)
void k_bscan(const int* __restrict__ gcur, int* __restrict__ gbase,
             int* __restrict__ starts, unsigned short* __restrict__ A) {
    __shared__ int tmp[2][512];
    int t = threadIdx.x;
    if (t < HD) A[(size_t)NN * HD + t] = 0x7F80;   // bf16 +inf sentinel row
    int v = (t < NBKT) ? gcur[t] : 0;
    int p = 0;
    tmp[0][t] = v;
    __syncthreads();
#pragma unroll
    for (int off = 1; off < 512; off <<= 1) {
        int nv = tmp[p][t] + ((t >= off) ? tmp[p][t - off] : 0);
        tmp[p ^ 1][t] = nv; p ^= 1;
        __syncthreads();
    }
    if (t < NBKT) gbase[t] = tmp[p][t] - v;
    if (t == 0) { gbase[NBKT] = NE; starts[NN] = NE; }
}

__global__ __launch_bounds__(256)
void k_phaseB(const unsigned int* __restrict__ ebuf, const int* __restrict__ gcur,
              const int* __restrict__ gbase, int* __restrict__ starts,
              int* __restrict__ ssrc) {
    __shared__ int hist[256];
    __shared__ int tmp[2][256];
    __shared__ int cur[256];
    int b = blockIdx.x;
    int eb0 = b * EPBKT;
    int cntb = gcur[b];
    int go = gbase[b];
    int t = threadIdx.x;
    hist[t] = 0;
    __syncthreads();
    for (int i = t; i < cntb; i += 256)
        atomicAdd(&hist[ebuf[eb0 + i] >> 24], 1);
    __syncthreads();
    int v = hist[t];
    int p = 0;
    tmp[0][t] = v;
    __syncthreads();
#pragma unroll
    for (int off = 1; off < 256; off <<= 1) {
        int nv = tmp[p][t] + ((t >= off) ? tmp[p][t - off] : 0);
        tmp[p ^ 1][t] = nv; p ^= 1;
        __syncthreads();
    }
    int excl = tmp[p][t] - v;
    cur[t] = excl;
    int node = b * 256 + t;
    if (node < NN) starts[node] = go + excl;
    __syncthreads();
    for (int i = t; i < cntb; i += 256) {
        unsigned e = ebuf[eb0 + i];
        int ld = e >> 24;
        int pos = go + atomicAdd(&cur[ld], 1);
        ssrc[pos] = e & 0xFFFFFF;
    }
}

// ---- node GEMM via v_dot2_f32_f16: operands packed f16-pairs along K in LDS ----
// If x != null (layer 1): h-tile computed on the fly as tanh(x@Wi+bi) -- h array
// is not touched (k_input is fused away).  Otherwise reads h (updated in place
// by the previous k_edge).
// A-output holds EA = 2^{clamp(c*(h@Wtop + b)/2, +-126)} as bf16.
// B-output holds EB = 2^{clamp(c*(h@Wbot)/2,     +-126)} as f32.
// Edge sigmoid term becomes 1/(1 + (EA*EB)^2): no exp2 in the edge loop.
__global__ __launch_bounds__(256)
void k_nodemm(const float* __restrict__ h, const float* __restrict__ x,
              const float* __restrict__ Wi, const float* __restrict__ bi,
              const float* __restrict__ W, const float* __restrict__ bias,
              unsigned short* __restrict__ A, float* __restrict__ B) {
    __shared__ unsigned ht_p[32][68];      // [k-pair][row(+pad)]  8.7 KB
    __shared__ unsigned ws_p[2][32][64];   // [half][k-pair][col]  16.4 KB
    int m0 = blockIdx.x * 64;
    int tid = threadIdx.x;
    const float4* W4 = (const float4*)W;
    // stage W packed along K: (h,k2,c4), 1024 tasks
    for (int i = tid; i < 1024; i += 256) {
        int c4 = i & 15, k2 = (i >> 4) & 31, hh = i >> 9;
        float4 a = W4[(hh * 64 + 2 * k2) * 16 + c4];
        float4 b = W4[(hh * 64 + 2 * k2 + 1) * 16 + c4];
        uint4 pk;
        pk.x = pkh(a.x, b.x); pk.y = pkh(a.y, b.y);
        pk.z = pkh(a.z, b.z); pk.w = pkh(a.w, b.w);
        *(uint4*)&ws_p[hh][k2][c4 * 4] = pk;
    }
    // stage h tile, packed along K, transposed (layer 1: compute from x)
    for (int i = tid; i < 1024; i += 256) {
        int r = i >> 4, c4 = i & 15;
        int row = m0 + r;
        float4 v = make_float4(0.f, 0.f, 0.f, 0.f);
        if (row < NN) {
            if (x) {
                float4 xv = ((const float4*)x)[row];
                float4 w0 = ((const float4*)Wi)[0 * 16 + c4];
                float4 w1 = ((const float4*)Wi)[1 * 16 + c4];
                float4 w2 = ((const float4*)Wi)[2 * 16 + c4];
                float4 w3 = ((const float4*)Wi)[3 * 16 + c4];
                float4 bb = ((const float4*)bi)[c4];
                v.x = fast_tanh(bb.x + xv.x * w0.x + xv.y * w1.x + xv.z * w2.x + xv.w * w3.x);
                v.y = fast_tanh(bb.y + xv.x * w0.y + xv.y * w1.y + xv.z * w2.y + xv.w * w3.y);
                v.z = fast_tanh(bb.z + xv.x * w0.z + xv.y * w1.z + xv.z * w2.z + xv.w * w3.z);
                v.w = fast_tanh(bb.w + xv.x * w0.w + xv.y * w1.w + xv.z * w2.w + xv.w * w3.w);
            } else {
                v = ((const float4*)h)[row * 16 + c4];
            }
        }
        ht_p[2 * c4][r]     = pkh(v.x, v.y);
        ht_p[2 * c4 + 1][r] = pkh(v.z, v.w);
    }
    __syncthreads();
    int tn = tid & 15;
    int tm = tid >> 4;
    bool isA = (tn < 8);
    const unsigned* Wb = &ws_p[isA ? 0 : 1][0][(tn & 7) * 8];
    float acc[4][8];
#pragma unroll
    for (int i = 0; i < 4; ++i)
#pragma unroll
        for (int j = 0; j < 8; ++j)
            acc[i][j] = isA ? bias[(tn & 7) * 8 + j] : 0.f;
#pragma unroll 8
    for (int k2 = 0; k2 < 32; ++k2) {
        uint4 hv = *(const uint4*)&ht_p[k2][tm * 4];
        uint4 w0 = *(const uint4*)&Wb[k2 * 64];
        uint4 w1 = *(const uint4*)&Wb[k2 * 64 + 4];
        h2 hh[4] = {u2h(hv.x), u2h(hv.y), u2h(hv.z), u2h(hv.w)};
        h2 ww[8] = {u2h(w0.x), u2h(w0.y), u2h(w0.z), u2h(w0.w),
                    u2h(w1.x), u2h(w1.y), u2h(w1.z), u2h(w1.w)};
#pragma unroll
        for (int i = 0; i < 4; ++i)
#pragma unroll
            for (int j = 0; j < 8; ++j)
                acc[i][j] = __builtin_amdgcn_fdot2(hh[i], ww[j], acc[i][j], false);
    }
#pragma unroll
    for (int i = 0; i < 4; ++i) {
        int node = m0 + tm * 4 + i;
        if (node >= NN) break;
        if (isA) {
            uint4 pk;
            pk.x = (unsigned)f2bf(exph(acc[i][0])) | ((unsigned)f2bf(exph(acc[i][1])) << 16);
            pk.y = (unsigned)f2bf(exph(acc[i][2])) | ((unsigned)f2bf(exph(acc[i][3])) << 16);
            pk.z = (unsigned)f2bf(exph(acc[i][4])) | ((unsigned)f2bf(exph(acc[i][5])) << 16);
            pk.w = (unsigned)f2bf(exph(acc[i][6])) | ((unsigned)f2bf(exph(acc[i][7])) << 16);
            ((uint4*)A)[node * 8 + tn] = pk;
        } else {
            ((float4*)B)[node * 16 + (tn & 7) * 2 + 0] =
                make_float4(exph(acc[i][0]), exph(acc[i][1]),
                            exph(acc[i][2]), exph(acc[i][3]));
            ((float4*)B)[node * 16 + (tn & 7) * 2 + 1] =
                make_float4(exph(acc[i][4]), exph(acc[i][5]),
                            exph(acc[i][6]), exph(acc[i][7]));
        }
    }
}

// -------- edge kernel: applies the aggregation delta to h IN PLACE --------
// term = 1/(1 + (EA[s,j]*EB[d,j])^2); mul+fma+rcp+add per element (no exp2).
// deg <= 32 (99.99% of nodes): the ENTIRE node is one self-contained padded
// block -> ONE vmcnt latency group.  Pad lanes carry idx = NN -> +inf
// sentinel row -> term exactly 0.  m is wave-uniform: non-divergent switch.
// If h16 != null (last layer): h_new is written as PACKED F16 PAIRS (the same
// cvt_pkrtz rounding k_out_fused used to apply during staging -> bit-identical
// values downstream) -- halves the L3 h handoff traffic; f32 h is not written.
#define BODYN(N) { \
    unsigned short va[N]; \
    _Pragma("unroll") \
    for (int u = 0; u < N; ++u) { \
        int s = __builtin_amdgcn_readlane(idx, k + u); \
        va[u] = A[s * HD + j]; \
    } \
    _Pragma("unroll") \
    for (int u = 0; u < N; u += 2) { \
        float pa = bf2f(va[u]) * eb; \
        float pb = bf2f(va[u + 1]) * eb; \
        acc0 += __builtin_amdgcn_rcpf(fmaf(pa, pa, 1.f)); \
        acc1 += __builtin_amdgcn_rcpf(fmaf(pb, pb, 1.f)); \
    } \
}

__global__ __launch_bounds__(256)
void k_edge(const unsigned short* __restrict__ A, const float* __restrict__ B,
            float* __restrict__ h,
            const int* __restrict__ starts, const int* __restrict__ ssrc,
            const float* __restrict__ x, const float* __restrict__ Wi,
            const float* __restrict__ bi,
            unsigned* __restrict__ h16) {
    int g = blockIdx.x * 256 + threadIdx.x;
    int d = g >> 6, j = g & 63;
    if (d >= NN) return;
    int s0 = starts[d], s1 = starts[d + 1];
    float eb = B[d * HD + j];
    float hv;
    if (x) {
        float x0 = x[d * 4 + 0], x1 = x[d * 4 + 1];
        float x2 = x[d * 4 + 2], x3 = x[d * 4 + 3];
        hv = fast_tanh(bi[j] + x0 * Wi[j] + x1 * Wi[HD + j]
                             + x2 * Wi[2 * HD + j] + x3 * Wi[3 * HD + j]);
    } else {
        hv = h[d * HD + j];
    }
    float acc0 = 0.f, acc1 = 0.f;
    for (int base = s0; base < s1; base += 64) {
        int m = min(s1 - base, 64);
        int idx = (base + j < s1) ? ssrc[base + j] : NN;   // pad lanes -> sentinel
        if (m <= 32) {
            // whole node in ONE latency group (4-granular pad, ~9% overhead)
            int k = 0;
            int nq = (m + 3) >> 2;           // 1..8 quads
            switch (nq) {
                case 1: BODYN(4)  break;
                case 2: BODYN(8)  break;
                case 3: BODYN(12) break;
                case 4: BODYN(16) break;
                case 5: BODYN(20) break;
                case 6: BODYN(24) break;
                case 7: BODYN(28) break;
                default: BODYN(32) break;
            }
        } else {
            int k = 0;
            for (; k + 16 <= m; k += 16) {
                unsigned short va[16];
#pragma unroll
                for (int u = 0; u < 16; ++u) {
                    int s = __builtin_amdgcn_readlane(idx, k + u);   // SGPR src id
                    va[u] = A[s * HD + j];                           // one load group
                }
#pragma unroll
                for (int u = 0; u < 16; u += 2) {
                    float pa = bf2f(va[u]) * eb;
                    float pb = bf2f(va[u + 1]) * eb;
                    acc0 += __builtin_amdgcn_rcpf(fmaf(pa, pa, 1.f));
                    acc1 += __builtin_amdgcn_rcpf(fmaf(pb, pb, 1.f));
                }
            }
            int r = m - k;                       // 0..15
            if (r) {
                int nq = (r + 3) >> 2;           // 1..4 quads, padded w/ sentinel
                if (nq == 4)      BODYN(16)
                else if (nq == 3) BODYN(12)
                else if (nq == 2) BODYN(8)
                else              BODYN(4)
            }
        }
    }
    float delta = (float)(s1 - s0) - 2.f * (acc0 + acc1);
    float hnew = hv + delta;
    if (h16) {
        float partner = __shfl_down(hnew, 1);
        if ((j & 1) == 0)
            h16[d * 32 + (j >> 1)] = pkh(hnew, partner);   // 128B/wave, coalesced
    } else {
        h[d * HD + j] = hnew;
    }
}
#undef BODYN

// ------- fused output MLP (dot2): out = tanh(h16@W1+b1)@W2+b2 -------
// h16 holds f16-packed h_new pairs from L3 k_edge (identical values to the
// pkh-staging this kernel previously applied to f32 h).
__global__ __launch_bounds__(256)
void k_out_fused(const unsigned* __restrict__ h16,
                 const float* __restrict__ W1, const float* __restrict__ b1,
                 const float* __restrict__ W2, const float* __restrict__ b2,
                 float* __restrict__ out) {
    __shared__ unsigned ht_p[32][68];    // 8.7 KB
    __shared__ unsigned ws_p[32][64];    // 8.2 KB
    int m0 = blockIdx.x * 64;
    int tid = threadIdx.x;
    const float4* W14 = (const float4*)W1;
    for (int i = tid; i < 512; i += 256) {
        int c4 = i & 15, k2 = i >> 4;
        float4 a = W14[(2 * k2) * 16 + c4];
        float4 b = W14[(2 * k2 + 1) * 16 + c4];
        uint4 pk;
        pk.x = pkh(a.x, b.x); pk.y = pkh(a.y, b.y);
        pk.z = pkh(a.z, b.z); pk.w = pkh(a.w, b.w);
        *(uint4*)&ws_p[k2][c4 * 4] = pk;
    }
    for (int i = tid; i < 1024; i += 256) {
        int r = i >> 4, c4 = i & 15;
        int row = m0 + r;
        uint2 hv = make_uint2(0u, 0u);         // f16 zeros for pad rows
        if (row < NN) hv = ((const uint2*)h16)[row * 16 + c4];
        ht_p[2 * c4][r]     = hv.x;
        ht_p[2 * c4 + 1][r] = hv.y;
    }
    __syncthreads();
    int tn = tid & 15;
    int tm = tid >> 4;
    float acc[4][4];
#pragma unroll
    for (int i = 0; i < 4; ++i)
#pragma unroll
        for (int jj = 0; jj < 4; ++jj)
            acc[i][jj] = b1[tn * 4 + jj];
#pragma unroll 8
    for (int k2 = 0; k2 < 32; ++k2) {
        uint4 hv = *(const uint4*)&ht_p[k2][tm * 4];
        uint4 wv = *(const uint4*)&ws_p[k2][tn * 4];
        h2 hh[4] = {u2h(hv.x), u2h(hv.y), u2h(hv.z), u2h(hv.w)};
        h2 ww[4] = {u2h(wv.x), u2h(wv.y), u2h(wv.z), u2h(wv.w)};
#pragma unroll
        for (int i = 0; i < 4; ++i)
#pragma unroll
            for (int jj = 0; jj < 4; ++jj)
                acc[i][jj] = __builtin_amdgcn_fdot2(hh[i], ww[jj], acc[i][jj], false);
    }
    float p[4][3];
#pragma unroll
    for (int i = 0; i < 4; ++i) { p[i][0] = 0.f; p[i][1] = 0.f; p[i][2] = 0.f; }
#pragma unroll
    for (int jj = 0; jj < 4; ++jj) {
        int jcol = tn * 4 + jj;
        float w0 = W2[jcol * 3 + 0], w1 = W2[jcol * 3 + 1], w2 = W2[jcol * 3 + 2];
#pragma unroll
        for (int i = 0; i < 4; ++i) {
            float t = fast_tanh(acc[i][jj]);
            p[i][0] += t * w0; p[i][1] += t * w1; p[i][2] += t * w2;
        }
    }
#pragma unroll
    for (int off = 1; off < 16; off <<= 1) {
#pragma unroll
        for (int i = 0; i < 4; ++i) {
            p[i][0] += __shfl_xor(p[i][0], off);
            p[i][1] += __shfl_xor(p[i][1], off);
            p[i][2] += __shfl_xor(p[i][2], off);
        }
    }
    if (tn == 0) {
#pragma unroll
        for (int i = 0; i < 4; ++i) {
            int node = m0 + tm * 4 + i;
            if (node < NN) {
                out[node * 3 + 0] = p[i][0] + b2[0];
                out[node * 3 + 1] = p[i][1] + b2[1];
                out[node * 3 + 2] = p[i][2] + b2[2];
            }
        }
    }
}

extern "C" void kernel_launch(void* const* d_in, const int* in_sizes, int n_in,
                              void* d_out, int out_size, void* d_ws, size_t ws_size,
                              hipStream_t stream) {
    const float* x   = (const float*)d_in[0];
    const int*   ei  = (const int*)d_in[1];
    const float* Win = (const float*)d_in[2];
    const float* bin = (const float*)d_in[3];
    const float* Ws  = (const float*)d_in[4];
    const float* bs  = (const float*)d_in[5];
    const float* Wo1 = (const float*)d_in[6];
    const float* bo1 = (const float*)d_in[7];
    const float* Wo2 = (const float*)d_in[8];
    const float* bo2 = (const float*)d_in[9];
    float* out = (float*)d_out;

    char* p = (char*)d_ws;
    auto alloc = [&](size_t bytes) {
        char* r = p;
        p += (bytes + 15) & ~size_t(15);
        return r;
    };
    // total ~83.7 MB (proven-safe envelope); A has +1 sentinel row
    float* h            = (float*)alloc((size_t)NN * HD * 4);            // 25.6 MB
    float* Bm           = (float*)alloc((size_t)NN * HD * 4);            // 25.6 MB
    unsigned short* A   = (unsigned short*)alloc((size_t)(NN + 1) * HD * 2); // 12.8 MB
    unsigned int* ebuf  = (unsigned int*)alloc((size_t)NBKT * EPBKT * 4);// 12.81 MB
    int* starts         = (int*)alloc((size_t)(NN + 1) * 4);             // 0.4 MB
    int* ssrc           = (int*)alloc((size_t)NE * 4);                   // 6.4 MB
    int* gcur           = (int*)alloc((NBKT + 1) * 4);
    int* gbase          = (int*)alloc((NBKT + 1) * 4);
    // ebuf is dead after the CSR build; reuse it as the f16 h handoff buffer
    // (NN*HD*2 = 12.8 MB <= 12.81 MB; rewritten by phaseA each replay).
    unsigned* h16       = (unsigned*)ebuf;

    const int* src = ei;
    const int* dst = ei + NE;

    // ---- edge CSR build (+ sentinel-row fill in k_bscan) ----
    k_zero<<<(NBKT + 255) / 256, 256, 0, stream>>>(gcur, NBKT);
    k_phaseA<<<NBLKA, 256, 0, stream>>>(src, dst, gcur, ebuf);
    k_bscan<<<1, 512, 0, stream>>>(gcur, gbase, starts, A);
    k_phaseB<<<NBKT, 256, 0, stream>>>(ebuf, gcur, gbase, starts, ssrc);

    // ---- pipeline (k_input fused into L1; L3 hands h to out_fused as f16) ----
    k_nodemm<<<NMBLK, 256, 0, stream>>>(h, x, Win, bin, Ws, bs, A, Bm);
    k_edge<<<(NN * HD + 255) / 256, 256, 0, stream>>>(A, Bm, h, starts, ssrc, x, Win, bin,
                                                      nullptr);

    k_nodemm<<<NMBLK, 256, 0, stream>>>(h, nullptr, nullptr, nullptr,
                                        Ws + (size_t)1 * 2 * HD * HD, bs + HD, A, Bm);
    k_edge<<<(NN * HD + 255) / 256, 256, 0, stream>>>(A, Bm, h, starts, ssrc,
                                                      nullptr, nullptr, nullptr, nullptr);

    k_nodemm<<<NMBLK, 256, 0, stream>>>(h, nullptr, nullptr, nullptr,
                                        Ws + (size_t)2 * 2 * HD * HD, bs + 2 * HD, A, Bm);
    k_edge<<<(NN * HD + 255) / 256, 256, 0, stream>>>(A, Bm, h, starts, ssrc,
                                                      nullptr, nullptr, nullptr, h16);

    k_out_fused<<<NMBLK, 256, 0, stream>>>(h16, Wo1, bo1, Wo2, bo2, out);
}